// Round 6
// baseline (575.833 us; speedup 1.0000x reference)
//
#include <hip/hip_runtime.h>
#include <cstdint>

typedef __bf16 bf16;
typedef __attribute__((ext_vector_type(8))) __bf16 bf16x8;
typedef __attribute__((ext_vector_type(4))) __bf16 bf16x4;
typedef __attribute__((ext_vector_type(4))) float f32x4;

#define B_   2
#define S_   2048
#define D_   2048
#define HKV_ 8
#define H_   32
#define DH_  64

#if __has_builtin(__builtin_amdgcn_exp2f)
#define EXP2(x) __builtin_amdgcn_exp2f(x)
#else
#define EXP2(x) __expf((x) * 0.6931471805599453f)
#endif

__device__ __forceinline__ void async_cp16(const bf16* g, bf16* l) {
  __builtin_amdgcn_global_load_lds(
      (__attribute__((address_space(1))) void*)g,
      (__attribute__((address_space(3))) void*)l,
      16, 0, 0);
}

// ------- weight transpose + downcast: in[R][C] fp32 -> out[C][R] bf16 -------
__global__ __launch_bounds__(256) void transpose_k(
    const float* __restrict__ in, bf16* __restrict__ out, int R, int C) {
  __shared__ bf16 tile[64][65];
  const int tx = threadIdx.x & 63;
  const int ty = threadIdx.x >> 6;   // 0..3
  const int r0 = blockIdx.x * 64;
  const int c0 = blockIdx.y * 64;
#pragma unroll
  for (int j = 0; j < 16; ++j) {
    int r = j * 4 + ty;
    tile[r][tx] = (bf16)in[(size_t)(r0 + r) * C + c0 + tx];
  }
  __syncthreads();
#pragma unroll
  for (int j = 0; j < 16; ++j) {
    int r = j * 4 + ty;
    out[(size_t)(c0 + r) * R + r0 + tx] = tile[tx][r];
  }
}

// ---- C = A[M,K] @ Bt[N,K]^T + bias. fp32 accum. m97-style global_load_lds
// staging. OMODE 2: fp32 row-major out (C0). OMODE 3: fused QKV epilogue:
//   col<2048 -> Qs(C0) bf16 scaled log2e/8; col<2560 -> Kb(C1); else VT(C2).
template <typename AT, int OMODE>
__global__ __launch_bounds__(256) void gemm_bt(
    const AT* __restrict__ A, const bf16* __restrict__ Bt,
    const float* __restrict__ b1, const float* __restrict__ b2,
    const float* __restrict__ b3,
    void* __restrict__ C0, void* __restrict__ C1, void* __restrict__ C2,
    int N, int K) {
  __shared__ bf16 a_tile[128 * 64];
  __shared__ bf16 b_tile[128 * 64];
  const int tid  = threadIdx.x;
  const int wave = tid >> 6;
  const int lane = tid & 63;
  const int quad = lane >> 4;
  const int l16  = lane & 15;
  const int m0   = blockIdx.x * 128;
  const int n0   = blockIdx.y * 128;
  const int wm   = (wave >> 1) * 64;
  const int wn   = (wave & 1) * 64;

  f32x4 acc[4][4] = {};

  const int srow  = wave * 32 + (lane >> 3);
  const int skoff = (lane & 7) * 8;
  const AT*   Ag = A  + (size_t)(m0 + srow) * K + skoff;
  const bf16* Bg = Bt + (size_t)(n0 + srow) * K + skoff;
  bf16* al = &a_tile[srow * 64 + skoff];
  bf16* bl = &b_tile[srow * 64 + skoff];

  for (int kt = 0; kt < K; kt += 64) {
    bf16x8 areg[4];
    if constexpr (sizeof(AT) == 4) {
#pragma unroll
      for (int c = 0; c < 4; ++c) {
        const float* ap = (const float*)(Ag + (size_t)(c * 8) * K + kt);
        float4 lo = *(const float4*)ap;
        float4 hi = *(const float4*)(ap + 4);
        areg[c][0] = (bf16)lo.x; areg[c][1] = (bf16)lo.y;
        areg[c][2] = (bf16)lo.z; areg[c][3] = (bf16)lo.w;
        areg[c][4] = (bf16)hi.x; areg[c][5] = (bf16)hi.y;
        areg[c][6] = (bf16)hi.z; areg[c][7] = (bf16)hi.w;
      }
    }
    __syncthreads();
    if constexpr (sizeof(AT) == 4) {
#pragma unroll
      for (int c = 0; c < 4; ++c) *(bf16x8*)(al + c * 512) = areg[c];
    } else {
#pragma unroll
      for (int c = 0; c < 4; ++c)
        async_cp16((const bf16*)Ag + (size_t)(c * 8) * K + kt, al + c * 512);
    }
#pragma unroll
    for (int c = 0; c < 4; ++c)
      async_cp16(Bg + (size_t)(c * 8) * K + kt, bl + c * 512);
    __syncthreads();
#pragma unroll
    for (int kk = 0; kk < 64; kk += 32) {
      bf16x8 af[4], bfr[4];
#pragma unroll
      for (int i = 0; i < 4; ++i) {
        af[i]  = *(const bf16x8*)&a_tile[(wm + i * 16 + l16) * 64 + kk + quad * 8];
        bfr[i] = *(const bf16x8*)&b_tile[(wn + i * 16 + l16) * 64 + kk + quad * 8];
      }
#pragma unroll
      for (int i = 0; i < 4; ++i)
#pragma unroll
        for (int j = 0; j < 4; ++j)
          acc[i][j] = __builtin_amdgcn_mfma_f32_16x16x32_bf16(af[i], bfr[j], acc[i][j], 0, 0, 0);
    }
  }

#pragma unroll
  for (int i = 0; i < 4; ++i) {
    const int row = m0 + wm + i * 16 + quad * 4;
#pragma unroll
    for (int j = 0; j < 4; ++j) {
      const int col = n0 + wn + j * 16 + l16;
      if constexpr (OMODE == 2) {
        const float bia = b1[col];
#pragma unroll
        for (int r = 0; r < 4; ++r)
          ((float*)C0)[(size_t)(row + r) * N + col] = acc[i][j][r] + bia;
      } else {  // OMODE 3: fused QKV
        if (col < 2048) {
          const float bia = b1[col];
#pragma unroll
          for (int r = 0; r < 4; ++r)
            ((bf16*)C0)[(size_t)(row + r) * 2048 + col] =
                (bf16)((acc[i][j][r] + bia) * 0.1803368801111244f);  // log2e/8
        } else if (col < 2560) {
          const int cc = col - 2048;
          const float bia = b2[cc];
#pragma unroll
          for (int r = 0; r < 4; ++r)
            ((bf16*)C1)[(size_t)(row + r) * 512 + cc] = (bf16)(acc[i][j][r] + bia);
        } else {
          const int cc = col - 2560;
          const float bia = b3[cc];
          const int hh = cc >> 6, dd = cc & 63;
#pragma unroll
          for (int r = 0; r < 4; ++r) {
            const int rr = row + r;
            const int bb = rr >> 11, ss = rr & 2047;
            ((bf16*)C2)[((((size_t)bb * HKV_ + hh) * DH_ + dd) << 11) + ss] =
                (bf16)(acc[i][j][r] + bia);
          }
        }
      }
    }
  }
}

// ---------------- flash GQA (S^T form, no max-shift, 64 q/wave) ------------
// grid (S/256, H, B), block 256. Q pre-scaled by log2e/8; p = exp2(st).
// Each wave: 64 queries (4 m-tiles), keys in 64-wide halves so st[4][4] fits.
// k-frags and V-frags are loaded once and reused across all 4 im -> LDS
// traffic per FLOP drops ~2.4x vs round 5 (the measured bottleneck).
__global__ __launch_bounds__(256, 2) void gqa_flash(
    const bf16* __restrict__ Qs,   // [B*S, D]
    const bf16* __restrict__ Kb,   // [B*S, HKV*DH]
    const bf16* __restrict__ VT,   // [B,HKV,DH,S]
    bf16* __restrict__ ctx) {      // [B*S, D]
  __shared__ bf16 k_tile[128 * 72];       // [key][dh], padded (stagger 4)
  __shared__ bf16 vt_tile[64 * 136];      // [dh][key], padded (stagger 4)
  __shared__ bf16 p_tile[4][16 * 72];     // per-wave [query16][key64], padded

  const int tid  = threadIdx.x;
  const int wave = tid >> 6;
  const int lane = tid & 63;
  const int quad = lane >> 4;
  const int l16  = lane & 15;

  const int qt = blockIdx.x;   // 8 tiles of 256 queries
  const int hq = blockIdx.y;
  const int b  = blockIdx.z;
  const int h  = hq >> 2;

  // Q fragments (MFMA B operand: n=query=l16, k=dh), 4 m-tiles per wave
  bf16x8 qf[4][2];
  const int qrow0 = b * S_ + qt * 256 + wave * 64;
#pragma unroll
  for (int im = 0; im < 4; ++im)
#pragma unroll
    for (int kk = 0; kk < 2; ++kk)
      qf[im][kk] = *(const bf16x8*)&Qs[(size_t)(qrow0 + im * 16 + l16) * D_ +
                                       hq * DH_ + kk * 32 + quad * 8];

  f32x4 o_acc[4][4] = {};                  // O^T: row=dh, col=query
  float l_run[4] = {0.f, 0.f, 0.f, 0.f};

  const int srow  = wave * 32 + (lane >> 3);
  const int skoff = (lane & 7) * 8;
  const int vrow  = wave * 16 + (lane >> 4);
  const int vkoff = (lane & 15) * 8;
  const bf16* Kg = Kb + (size_t)(b * S_ + srow) * (HKV_ * DH_) + h * DH_ + skoff;
  const bf16* Vg = VT + ((size_t)(b * HKV_ + h) * DH_ + vrow) * S_ + vkoff;
  bf16* kl = &k_tile[srow * 72 + skoff];
  bf16* vl = &vt_tile[vrow * 136 + vkoff];
  bf16* pw = &p_tile[wave][l16 * 72];

  // prefetch tile 0
  bf16x8 kreg[4], vreg[4];
#pragma unroll
  for (int c = 0; c < 4; ++c) {
    kreg[c] = *(const bf16x8*)(Kg + (size_t)(c * 8) * (HKV_ * DH_));
    vreg[c] = *(const bf16x8*)(Vg + (size_t)(c * 4) * S_);
  }

  for (int kt = 0; kt < S_; kt += 128) {
    __syncthreads();
#pragma unroll
    for (int c = 0; c < 4; ++c) {
      *(bf16x8*)(kl + c * 8 * 72)  = kreg[c];
      *(bf16x8*)(vl + c * 4 * 136) = vreg[c];
    }
    __syncthreads();

    if (kt + 128 < S_) {
      const int ktn = kt + 128;
#pragma unroll
      for (int c = 0; c < 4; ++c) {
        kreg[c] = *(const bf16x8*)(Kg + (size_t)(ktn + c * 8) * (HKV_ * DH_));
        vreg[c] = *(const bf16x8*)(Vg + (size_t)(c * 4) * S_ + ktn);
      }
    }

#pragma unroll
    for (int half = 0; half < 2; ++half) {
      // hoist V^T A-frags for this 64-key half (reused by all 4 im)
      bf16x8 av[2][4];
#pragma unroll
      for (int kq = 0; kq < 2; ++kq)
#pragma unroll
        for (int jm = 0; jm < 4; ++jm)
          av[kq][jm] = *(const bf16x8*)&vt_tile[(jm * 16 + l16) * 136 +
                                                half * 64 + kq * 32 + quad * 8];

      // S^T = K·Q^T for 64 keys x 64 queries; each ak serves 4 MFMAs
      f32x4 st[4][4] = {};
#pragma unroll
      for (int kk = 0; kk < 2; ++kk)
#pragma unroll
        for (int in = 0; in < 4; ++in) {
          bf16x8 ak = *(const bf16x8*)&k_tile[(half * 64 + in * 16 + l16) * 72 +
                                              kk * 32 + quad * 8];
#pragma unroll
          for (int im = 0; im < 4; ++im)
            st[im][in] = __builtin_amdgcn_mfma_f32_16x16x32_bf16(ak, qf[im][kk], st[im][in], 0, 0, 0);
        }

#pragma unroll
      for (int im = 0; im < 4; ++im) {
        float sm = 0.f;
#pragma unroll
        for (int in = 0; in < 4; ++in) {
          bf16x4 pv;
#pragma unroll
          for (int r = 0; r < 4; ++r) {
            float p = EXP2(st[im][in][r]);
            sm += p;
            pv[r] = (bf16)p;
          }
          *(bf16x4*)(pw + in * 16 + quad * 4) = pv;  // per-wave, no barrier
        }
        sm += __shfl_xor(sm, 16);
        sm += __shfl_xor(sm, 32);
        l_run[im] += sm;

#pragma unroll
        for (int kq = 0; kq < 2; ++kq) {
          bf16x8 pb = *(const bf16x8*)(pw + kq * 32 + quad * 8);
#pragma unroll
          for (int jm = 0; jm < 4; ++jm)
            o_acc[im][jm] = __builtin_amdgcn_mfma_f32_16x16x32_bf16(av[kq][jm], pb, o_acc[im][jm], 0, 0, 0);
        }
      }
    }
  }

  // epilogue: O^T row=dh=jm*16+quad*4+r, col=query=l16 -> ctx[query][dh]
#pragma unroll
  for (int im = 0; im < 4; ++im) {
    const float inv_l = 1.f / l_run[im];
    const size_t row = (size_t)(qrow0 + im * 16 + l16);
#pragma unroll
    for (int jm = 0; jm < 4; ++jm) {
      bf16x4 ov;
#pragma unroll
      for (int r = 0; r < 4; ++r) ov[r] = (bf16)(o_acc[im][jm][r] * inv_l);
      *(bf16x4*)&ctx[row * D_ + hq * DH_ + jm * 16 + quad * 4] = ov;
    }
  }
}

extern "C" void kernel_launch(void* const* d_in, const int* in_sizes, int n_in,
                              void* d_out, int out_size, void* d_ws, size_t ws_size,
                              hipStream_t stream) {
  const float* x  = (const float*)d_in[0];
  const float* Wq = (const float*)d_in[1];
  const float* bq = (const float*)d_in[2];
  const float* Wk = (const float*)d_in[3];
  const float* bk = (const float*)d_in[4];
  const float* Wv = (const float*)d_in[5];
  const float* bv = (const float*)d_in[6];
  const float* Wo = (const float*)d_in[7];
  const float* bo = (const float*)d_in[8];
  float* out = (float*)d_out;

  // ws (50.33 MB, proven):
  //   [0, 16.78M):      WT [3072][2048] bf16, then ctx [4096][2048] bf16
  //   [16.78M, 25.17M): WoT [2048][2048] bf16
  //   [25.17M, 41.94M): Qs  [4096][2048] bf16 (pre-scaled log2e/8)
  //   [41.94M, 46.14M): Kb  [4096][512] bf16
  //   [46.14M, 50.33M): VT  [2][8][64][2048] bf16
  char* ws = (char*)d_ws;
  bf16* WT  = (bf16*)(ws);
  bf16* ctx = (bf16*)(ws);               // reuses WT region after QKV GEMM
  bf16* WoT = (bf16*)(ws + 16777216);
  bf16* Qs  = (bf16*)(ws + 25165824);
  bf16* Kb  = (bf16*)(ws + 41943040);
  bf16* VT  = (bf16*)(ws + 46137344);

  dim3 blk(256);
  transpose_k<<<dim3(32, 32), blk, 0, stream>>>(Wq, WT, 2048, 2048);
  transpose_k<<<dim3(32, 8),  blk, 0, stream>>>(Wk, WT + (size_t)2048 * 2048, 2048, 512);
  transpose_k<<<dim3(32, 8),  blk, 0, stream>>>(Wv, WT + (size_t)2560 * 2048, 2048, 512);
  transpose_k<<<dim3(32, 32), blk, 0, stream>>>(Wo, WoT, 2048, 2048);

  // fused QKV projection: [4096,2048] x [3072,2048]^T
  gemm_bt<float, 3><<<dim3(32, 24), blk, 0, stream>>>(
      x, WT, bq, bk, bv, Qs, Kb, VT, 3072, 2048);

  gqa_flash<<<dim3(8, 32, 2), blk, 0, stream>>>(Qs, Kb, VT, ctx);

  // output projection -> fp32
  gemm_bt<bf16, 2><<<dim3(32, 16), blk, 0, stream>>>(
      ctx, WoT, bo, nullptr, nullptr, out, nullptr, nullptr, 2048, 2048);
}

// Round 7
// 377.989 us; speedup vs baseline: 1.5234x; 1.5234x over previous
//
#include <hip/hip_runtime.h>
#include <cstdint>

typedef __bf16 bf16;
typedef __attribute__((ext_vector_type(8))) __bf16 bf16x8;
typedef __attribute__((ext_vector_type(4))) __bf16 bf16x4;
typedef __attribute__((ext_vector_type(4))) float f32x4;

#define B_   2
#define S_   2048
#define D_   2048
#define HKV_ 8
#define H_   32
#define DH_  64

#if __has_builtin(__builtin_amdgcn_exp2f)
#define EXP2(x) __builtin_amdgcn_exp2f(x)
#else
#define EXP2(x) __expf((x) * 0.6931471805599453f)
#endif

__device__ __forceinline__ void async_cp16(const bf16* g, bf16* l) {
  __builtin_amdgcn_global_load_lds(
      (__attribute__((address_space(1))) void*)g,
      (__attribute__((address_space(3))) void*)l,
      16, 0, 0);
}

// ------- weight transpose + downcast: in[R][C] fp32 -> out[C][R] bf16 -------
__global__ __launch_bounds__(256) void transpose_k(
    const float* __restrict__ in, bf16* __restrict__ out, int R, int C) {
  __shared__ bf16 tile[64][65];
  const int tx = threadIdx.x & 63;
  const int ty = threadIdx.x >> 6;   // 0..3
  const int r0 = blockIdx.x * 64;
  const int c0 = blockIdx.y * 64;
#pragma unroll
  for (int j = 0; j < 16; ++j) {
    int r = j * 4 + ty;
    tile[r][tx] = (bf16)in[(size_t)(r0 + r) * C + c0 + tx];
  }
  __syncthreads();
#pragma unroll
  for (int j = 0; j < 16; ++j) {
    int r = j * 4 + ty;
    out[(size_t)(c0 + r) * R + r0 + tx] = tile[tx][r];
  }
}

// ---- C = A[M,K] @ Bt[N,K]^T + bias. fp32 accum. m97-style global_load_lds
// staging. OMODE 2: fp32 row-major out (C0). OMODE 3: fused QKV epilogue:
//   col<2048 -> Qs(C0) bf16 scaled log2e/8; col<2560 -> Kb(C1); else VT(C2).
template <typename AT, int OMODE>
__global__ __launch_bounds__(256) void gemm_bt(
    const AT* __restrict__ A, const bf16* __restrict__ Bt,
    const float* __restrict__ b1, const float* __restrict__ b2,
    const float* __restrict__ b3,
    void* __restrict__ C0, void* __restrict__ C1, void* __restrict__ C2,
    int N, int K) {
  __shared__ bf16 a_tile[128 * 64];
  __shared__ bf16 b_tile[128 * 64];
  const int tid  = threadIdx.x;
  const int wave = tid >> 6;
  const int lane = tid & 63;
  const int quad = lane >> 4;
  const int l16  = lane & 15;
  const int m0   = blockIdx.x * 128;
  const int n0   = blockIdx.y * 128;
  const int wm   = (wave >> 1) * 64;
  const int wn   = (wave & 1) * 64;

  f32x4 acc[4][4] = {};

  const int srow  = wave * 32 + (lane >> 3);
  const int skoff = (lane & 7) * 8;
  const AT*   Ag = A  + (size_t)(m0 + srow) * K + skoff;
  const bf16* Bg = Bt + (size_t)(n0 + srow) * K + skoff;
  bf16* al = &a_tile[srow * 64 + skoff];
  bf16* bl = &b_tile[srow * 64 + skoff];

  for (int kt = 0; kt < K; kt += 64) {
    bf16x8 areg[4];
    if constexpr (sizeof(AT) == 4) {
#pragma unroll
      for (int c = 0; c < 4; ++c) {
        const float* ap = (const float*)(Ag + (size_t)(c * 8) * K + kt);
        float4 lo = *(const float4*)ap;
        float4 hi = *(const float4*)(ap + 4);
        areg[c][0] = (bf16)lo.x; areg[c][1] = (bf16)lo.y;
        areg[c][2] = (bf16)lo.z; areg[c][3] = (bf16)lo.w;
        areg[c][4] = (bf16)hi.x; areg[c][5] = (bf16)hi.y;
        areg[c][6] = (bf16)hi.z; areg[c][7] = (bf16)hi.w;
      }
    }
    __syncthreads();
    if constexpr (sizeof(AT) == 4) {
#pragma unroll
      for (int c = 0; c < 4; ++c) *(bf16x8*)(al + c * 512) = areg[c];
    } else {
#pragma unroll
      for (int c = 0; c < 4; ++c)
        async_cp16((const bf16*)Ag + (size_t)(c * 8) * K + kt, al + c * 512);
    }
#pragma unroll
    for (int c = 0; c < 4; ++c)
      async_cp16(Bg + (size_t)(c * 8) * K + kt, bl + c * 512);
    __syncthreads();
#pragma unroll
    for (int kk = 0; kk < 64; kk += 32) {
      bf16x8 af[4], bfr[4];
#pragma unroll
      for (int i = 0; i < 4; ++i) {
        af[i]  = *(const bf16x8*)&a_tile[(wm + i * 16 + l16) * 64 + kk + quad * 8];
        bfr[i] = *(const bf16x8*)&b_tile[(wn + i * 16 + l16) * 64 + kk + quad * 8];
      }
#pragma unroll
      for (int i = 0; i < 4; ++i)
#pragma unroll
        for (int j = 0; j < 4; ++j)
          acc[i][j] = __builtin_amdgcn_mfma_f32_16x16x32_bf16(af[i], bfr[j], acc[i][j], 0, 0, 0);
    }
  }

#pragma unroll
  for (int i = 0; i < 4; ++i) {
    const int row = m0 + wm + i * 16 + quad * 4;
#pragma unroll
    for (int j = 0; j < 4; ++j) {
      const int col = n0 + wn + j * 16 + l16;
      if constexpr (OMODE == 2) {
        const float bia = b1[col];
#pragma unroll
        for (int r = 0; r < 4; ++r)
          ((float*)C0)[(size_t)(row + r) * N + col] = acc[i][j][r] + bia;
      } else {  // OMODE 3: fused QKV
        if (col < 2048) {
          const float bia = b1[col];
#pragma unroll
          for (int r = 0; r < 4; ++r)
            ((bf16*)C0)[(size_t)(row + r) * 2048 + col] =
                (bf16)((acc[i][j][r] + bia) * 0.1803368801111244f);  // log2e/8
        } else if (col < 2560) {
          const int cc = col - 2048;
          const float bia = b2[cc];
#pragma unroll
          for (int r = 0; r < 4; ++r)
            ((bf16*)C1)[(size_t)(row + r) * 512 + cc] = (bf16)(acc[i][j][r] + bia);
        } else {
          const int cc = col - 2560;
          const float bia = b3[cc];
          const int hh = cc >> 6, dd = cc & 63;
#pragma unroll
          for (int r = 0; r < 4; ++r) {
            const int rr = row + r;
            const int bb = rr >> 11, ss = rr & 2047;
            ((bf16*)C2)[((((size_t)bb * HKV_ + hh) * DH_ + dd) << 11) + ss] =
                (bf16)(acc[i][j][r] + bia);
          }
        }
      }
    }
  }
}

// ---------------- flash GQA (S^T form, no max-shift, no P round-trip) -------
// grid (S/128, H, B), block 256, 32 q/wave. Q pre-scaled by log2e/8.
// Key trick: MFMA sums over k-slots symmetrically, so we permute the k-slot
// -> key mapping per (quad,j): key = kq*32 + (j>>2)*16 + quad*4 + (j&3).
// Under this permutation the PV B-operand (P^T fragment) is exactly the
// lane's own st registers (exp'd, packed) -- no LDS round-trip, no shuffles.
// The V A-fragment becomes two b64 reads (same bytes). ak and av fragments
// are each loaded once and shared across both im.
__global__ __launch_bounds__(256, 3) void gqa_flash(
    const bf16* __restrict__ Qs,   // [B*S, D]
    const bf16* __restrict__ Kb,   // [B*S, HKV*DH]
    const bf16* __restrict__ VT,   // [B,HKV,DH,S]
    bf16* __restrict__ ctx) {      // [B*S, D]
  __shared__ bf16 k_tile[128 * 72];       // [key][dh], padded
  __shared__ bf16 vt_tile[64 * 136];      // [dh][key], padded

  const int tid  = threadIdx.x;
  const int wave = tid >> 6;
  const int lane = tid & 63;
  const int quad = lane >> 4;
  const int l16  = lane & 15;

  const int qt = blockIdx.x;
  const int hq = blockIdx.y;
  const int b  = blockIdx.z;
  const int h  = hq >> 2;

  // Q fragments (MFMA B operand: n=query=l16, k=dh)
  bf16x8 qf[2][2];
  const int qrow0 = b * S_ + qt * 128 + wave * 32;
#pragma unroll
  for (int im = 0; im < 2; ++im)
#pragma unroll
    for (int kk = 0; kk < 2; ++kk)
      qf[im][kk] = *(const bf16x8*)&Qs[(size_t)(qrow0 + im * 16 + l16) * D_ +
                                       hq * DH_ + kk * 32 + quad * 8];

  f32x4 o_acc[2][4] = {};                  // O^T: row=dh, col=query
  float l_run[2] = {0.f, 0.f};

  const int srow  = wave * 32 + (lane >> 3);
  const int skoff = (lane & 7) * 8;
  const int vrow  = wave * 16 + (lane >> 4);
  const int vkoff = (lane & 15) * 8;
  const bf16* Kg = Kb + (size_t)(b * S_ + srow) * (HKV_ * DH_) + h * DH_ + skoff;
  const bf16* Vg = VT + ((size_t)(b * HKV_ + h) * DH_ + vrow) * S_ + vkoff;
  bf16* kl = &k_tile[srow * 72 + skoff];
  bf16* vl = &vt_tile[vrow * 136 + vkoff];

  // prefetch tile 0
  bf16x8 kreg[4], vreg[4];
#pragma unroll
  for (int c = 0; c < 4; ++c) {
    kreg[c] = *(const bf16x8*)(Kg + (size_t)(c * 8) * (HKV_ * DH_));
    vreg[c] = *(const bf16x8*)(Vg + (size_t)(c * 4) * S_);
  }

  for (int kt = 0; kt < S_; kt += 128) {
    __syncthreads();
#pragma unroll
    for (int c = 0; c < 4; ++c) {
      *(bf16x8*)(kl + c * 8 * 72)  = kreg[c];
      *(bf16x8*)(vl + c * 4 * 136) = vreg[c];
    }
    __syncthreads();

    if (kt + 128 < S_) {
      const int ktn = kt + 128;
#pragma unroll
      for (int c = 0; c < 4; ++c) {
        kreg[c] = *(const bf16x8*)(Kg + (size_t)(ktn + c * 8) * (HKV_ * DH_));
        vreg[c] = *(const bf16x8*)(Vg + (size_t)(c * 4) * S_ + ktn);
      }
    }

#pragma unroll
    for (int hf = 0; hf < 2; ++hf) {       // 64-key halves
      // S^T = K·Q^T: each ak fragment serves both im
      f32x4 st[2][4] = {};
#pragma unroll
      for (int kk = 0; kk < 2; ++kk)
#pragma unroll
        for (int in = 0; in < 4; ++in) {
          bf16x8 ak = *(const bf16x8*)&k_tile[(hf * 64 + in * 16 + l16) * 72 +
                                              kk * 32 + quad * 8];
          st[0][in] = __builtin_amdgcn_mfma_f32_16x16x32_bf16(ak, qf[0][kk], st[0][in], 0, 0, 0);
          st[1][in] = __builtin_amdgcn_mfma_f32_16x16x32_bf16(ak, qf[1][kk], st[1][in], 0, 0, 0);
        }

      // exp2 + pack into lane-local P fragments (permuted k-slot layout)
      bf16x8 pb[2][2];
#pragma unroll
      for (int im = 0; im < 2; ++im) {
        float sm = 0.f;
#pragma unroll
        for (int in = 0; in < 4; ++in)
#pragma unroll
          for (int r = 0; r < 4; ++r) {
            float p = EXP2(st[im][in][r]);
            sm += p;
            pb[im][in >> 1][(in & 1) * 4 + r] = (bf16)p;
          }
        sm += __shfl_xor(sm, 16);
        sm += __shfl_xor(sm, 32);
        l_run[im] += sm;
      }

      // O^T += V^T · P^T with the same permuted k-slot mapping:
      // A[m=l16][slot(quad,j)] = V^T[dh][key = base + (j>>2)*16 + quad*4 + (j&3)]
#pragma unroll
      for (int kq = 0; kq < 2; ++kq) {
        const int base = (hf * 2 + kq) * 32 + quad * 4;
#pragma unroll
        for (int jm = 0; jm < 4; ++jm) {
          const bf16* vp = &vt_tile[(jm * 16 + l16) * 136 + base];
          bf16x4 lo = *(const bf16x4*)vp;
          bf16x4 hi = *(const bf16x4*)(vp + 16);
          bf16x8 av;
#pragma unroll
          for (int r = 0; r < 4; ++r) { av[r] = lo[r]; av[4 + r] = hi[r]; }
          o_acc[0][jm] = __builtin_amdgcn_mfma_f32_16x16x32_bf16(av, pb[0][kq], o_acc[0][jm], 0, 0, 0);
          o_acc[1][jm] = __builtin_amdgcn_mfma_f32_16x16x32_bf16(av, pb[1][kq], o_acc[1][jm], 0, 0, 0);
        }
      }
    }
  }

  // epilogue: O^T row=dh=jm*16+quad*4+r, col=query=l16 -> ctx[query][dh]
#pragma unroll
  for (int im = 0; im < 2; ++im) {
    const float inv_l = 1.f / l_run[im];
    const size_t row = (size_t)(qrow0 + im * 16 + l16);
#pragma unroll
    for (int jm = 0; jm < 4; ++jm) {
      bf16x4 ov;
#pragma unroll
      for (int r = 0; r < 4; ++r) ov[r] = (bf16)(o_acc[im][jm][r] * inv_l);
      *(bf16x4*)&ctx[row * D_ + hq * DH_ + jm * 16 + quad * 4] = ov;
    }
  }
}

extern "C" void kernel_launch(void* const* d_in, const int* in_sizes, int n_in,
                              void* d_out, int out_size, void* d_ws, size_t ws_size,
                              hipStream_t stream) {
  const float* x  = (const float*)d_in[0];
  const float* Wq = (const float*)d_in[1];
  const float* bq = (const float*)d_in[2];
  const float* Wk = (const float*)d_in[3];
  const float* bk = (const float*)d_in[4];
  const float* Wv = (const float*)d_in[5];
  const float* bv = (const float*)d_in[6];
  const float* Wo = (const float*)d_in[7];
  const float* bo = (const float*)d_in[8];
  float* out = (float*)d_out;

  // ws (50.33 MB, proven):
  //   [0, 16.78M):      WT [3072][2048] bf16, then ctx [4096][2048] bf16
  //   [16.78M, 25.17M): WoT [2048][2048] bf16
  //   [25.17M, 41.94M): Qs  [4096][2048] bf16 (pre-scaled log2e/8)
  //   [41.94M, 46.14M): Kb  [4096][512] bf16
  //   [46.14M, 50.33M): VT  [2][8][64][2048] bf16
  char* ws = (char*)d_ws;
  bf16* WT  = (bf16*)(ws);
  bf16* ctx = (bf16*)(ws);               // reuses WT region after QKV GEMM
  bf16* WoT = (bf16*)(ws + 16777216);
  bf16* Qs  = (bf16*)(ws + 25165824);
  bf16* Kb  = (bf16*)(ws + 41943040);
  bf16* VT  = (bf16*)(ws + 46137344);

  dim3 blk(256);
  transpose_k<<<dim3(32, 32), blk, 0, stream>>>(Wq, WT, 2048, 2048);
  transpose_k<<<dim3(32, 8),  blk, 0, stream>>>(Wk, WT + (size_t)2048 * 2048, 2048, 512);
  transpose_k<<<dim3(32, 8),  blk, 0, stream>>>(Wv, WT + (size_t)2560 * 2048, 2048, 512);
  transpose_k<<<dim3(32, 32), blk, 0, stream>>>(Wo, WoT, 2048, 2048);

  // fused QKV projection: [4096,2048] x [3072,2048]^T
  gemm_bt<float, 3><<<dim3(32, 24), blk, 0, stream>>>(
      x, WT, bq, bk, bv, Qs, Kb, VT, 3072, 2048);

  gqa_flash<<<dim3(16, 32, 2), blk, 0, stream>>>(Qs, Kb, VT, ctx);

  // output projection -> fp32
  gemm_bt<bf16, 2><<<dim3(32, 16), blk, 0, stream>>>(
      ctx, WoT, bo, nullptr, nullptr, out, nullptr, nullptr, 2048, 2048);
}